// Round 11
// baseline (174.828 us; speedup 1.0000x reference)
//
#include <hip/hip_runtime.h>
#include <hip/hip_bf16.h>
#include <hip/hip_cooperative_groups.h>

namespace cg = cooperative_groups;

// PartitionedNormalization: per-domain BN stats (training mode) + affine.
// out[B][128] f32 = (gg+dg[s])*(x-mean[s])*rsqrt(var[s]+eps) + (gb+db[s])
//
// R11: single cooperative kernel (4 phases, 3 grid syncs). Phase1 = R10's
// verified half-wave-private LDS reduction. Gives rocprof visibility (one
// ~90us dispatch > the 76us harness fills) + removes 3 launches.

#define DIM 128
#define NDOM 8
#define PENT (NDOM + 2 * NDOM * DIM)  // 8 counts + 1024 sums + 1024 sqsums = 2056
#define EPSV 1e-3f
#define WREG 2048  // per half-wave region (floats): sums[8][128] | sqs[8][128]

__global__ __launch_bounds__(256) void pn_fused(
    const float4* __restrict__ x4, const int* __restrict__ seg,
    const float* __restrict__ gg, const float* __restrict__ gb,
    const float* __restrict__ dg, const float* __restrict__ db,
    float* __restrict__ partials, float* __restrict__ partials2,
    float* __restrict__ stats, float4* __restrict__ out, int B) {
  cg::grid_group grid = cg::this_grid();
  __shared__ float acc[8 * WREG];  // 64 KB -> 2 blocks/CU
  __shared__ float lcnt[NDOM];
  const int tid = threadIdx.x;
  const int NBLK = gridDim.x;
  const int chunk = B / NBLK;  // rows per block (512 at NBLK=512)
  const int row0blk = blockIdx.x * chunk;
  const int w = tid >> 6;  // wave 0..3
  const int l = tid & 63;
  const int h = l >> 5;    // half-wave: row parity
  const int g = l & 31;    // float4 col group
  float* reg = acc + (w * 2 + h) * WREG;  // half-wave private

  // ---- phase 1: per-block partial sums (R10 structure, race-free) ----
  for (int i = tid; i < 2 * WREG; i += 256)
    ((float4*)acc)[i] = make_float4(0.f, 0.f, 0.f, 0.f);
  if (tid < NDOM) lcnt[tid] = 0.f;
  __syncthreads();

  const int rowsPerWave = chunk >> 2;
  const int row0 = row0blk + w * rowsPerWave;

#define RMW(S, V)                                    \
  {                                                  \
    float* bs = reg + (S) * 128 + g * 4;             \
    float* bq = bs + NDOM * DIM;                     \
    float4 os = *(float4*)bs;                        \
    float4 oq = *(float4*)bq;                        \
    os.x += (V).x;                                   \
    os.y += (V).y;                                   \
    os.z += (V).z;                                   \
    os.w += (V).w;                                   \
    oq.x = fmaf((V).x, (V).x, oq.x);                 \
    oq.y = fmaf((V).y, (V).y, oq.y);                 \
    oq.z = fmaf((V).z, (V).z, oq.z);                 \
    oq.w = fmaf((V).w, (V).w, oq.w);                 \
    *(float4*)bs = os;                               \
    *(float4*)bq = oq;                               \
  }
  for (int it = 0; it < rowsPerWave; it += 8) {
    const int r = row0 + it;
    const int4 sgA = *(const int4*)(seg + r);
    const int4 sgB = *(const int4*)(seg + r + 4);
    const float4 v0 = x4[(size_t)(r + 0 + h) * 32 + g];
    const float4 v1 = x4[(size_t)(r + 2 + h) * 32 + g];
    const float4 v2 = x4[(size_t)(r + 4 + h) * 32 + g];
    const float4 v3 = x4[(size_t)(r + 6 + h) * 32 + g];
    const int s0 = h ? sgA.y : sgA.x;
    const int s1 = h ? sgA.w : sgA.z;
    const int s2 = h ? sgB.y : sgB.x;
    const int s3 = h ? sgB.w : sgB.z;
    RMW(s0, v0)
    RMW(s1, v1)
    RMW(s2, v2)
    RMW(s3, v3)
  }
#undef RMW
  __syncthreads();

  for (int i = tid; i < chunk; i += 256)
    atomicAdd(&lcnt[seg[row0blk + i]], 1.f);
  __syncthreads();

  {
    float* outp = partials + (size_t)blockIdx.x * PENT;
    if (tid < NDOM) outp[tid] = lcnt[tid];
    for (int i = tid; i < 2 * NDOM * DIM; i += 256) {
      float v = 0.f;
#pragma unroll
      for (int rr = 0; rr < 8; ++rr) v += acc[rr * WREG + i];
      outp[NDOM + i] = v;
    }
  }
  grid.sync();

  // ---- phase 2a: blocks 0..63 reduce NBLK partial rows -> 64 ----
  if (blockIdx.x < 64) {
    const int per = NBLK >> 6;
    const int b0 = blockIdx.x * per;
    float a2[9];
#pragma unroll
    for (int i = 0; i < 9; ++i) a2[i] = 0.f;
    for (int j = b0; j < b0 + per; ++j) {
      const float* p = partials + (size_t)j * PENT;
#pragma unroll
      for (int i = 0; i < 9; ++i) {
        const int e = tid + i * 256;
        if (e < PENT) a2[i] += p[e];
      }
    }
    float* o = partials2 + (size_t)blockIdx.x * PENT;
#pragma unroll
    for (int i = 0; i < 9; ++i) {
      const int e = tid + i * 256;
      if (e < PENT) o[e] = a2[i];
    }
  }
  grid.sync();

  // ---- phase 2b: blocks 0..3 -> scale/shift table ----
  if (blockIdx.x < 4) {
    const int t = blockIdx.x * 256 + tid;  // (k = t>>7, d = t&127)
    const int k = t >> 7;
    const int d = t & (DIM - 1);
    float c = 0.f, s = 0.f, q = 0.f;
    for (int j = 0; j < 64; ++j) {
      const float* p = partials2 + (size_t)j * PENT;
      c += p[k];
      s += p[NDOM + t];
      q += p[NDOM + NDOM * DIM + t];
    }
    const float n = fmaxf(c, 1.f);
    const float mean = s / n;
    const float var = fmaxf(q / n - mean * mean, 0.f);
    const float rstd = rsqrtf(var + EPSV);
    const float scale = (gg[d] + dg[t]) * rstd;
    const float shift = (gb[d] + db[t]) - scale * mean;
    stats[t] = scale;
    stats[NDOM * DIM + t] = shift;
  }
  grid.sync();

  // ---- phase 3: apply on own chunk ----
  {
    const int f40 = row0blk * 32;  // first float4 index of chunk
    const int nf4 = chunk * 32;
#pragma unroll 4
    for (int i = tid; i < nf4; i += 256) {
      const int gi = f40 + i;
      const int row = gi >> 5;
      const int c4 = gi & 31;
      const int s = seg[row];
      const float4 xv = x4[gi];
      const float4 a = ((const float4*)(stats + s * DIM))[c4];
      const float4 b = ((const float4*)(stats + NDOM * DIM + s * DIM))[c4];
      float4 o;
      o.x = fmaf(xv.x, a.x, b.x);
      o.y = fmaf(xv.y, a.y, b.y);
      o.z = fmaf(xv.z, a.z, b.z);
      o.w = fmaf(xv.w, a.w, b.w);
      out[gi] = o;
    }
  }
}

// ---------------- fallback path: R10 split kernels (known-good, 101us) ----------------
__global__ __launch_bounds__(256) void pn_reduce(const float4* __restrict__ x4,
                                                 const int* __restrict__ seg,
                                                 float* __restrict__ partials,
                                                 int rowsPerBlock) {
  __shared__ float acc[8 * WREG];
  __shared__ float lcnt[NDOM];
  const int tid = threadIdx.x;
  const int w = tid >> 6;
  const int l = tid & 63;
  const int h = l >> 5;
  const int g = l & 31;
  float* reg = acc + (w * 2 + h) * WREG;

  for (int i = tid; i < 2 * WREG; i += 256)
    ((float4*)acc)[i] = make_float4(0.f, 0.f, 0.f, 0.f);
  if (tid < NDOM) lcnt[tid] = 0.f;
  __syncthreads();

  const int rowsPerWave = rowsPerBlock >> 2;
  const int row0 = blockIdx.x * rowsPerBlock + w * rowsPerWave;

#define RMW(S, V)                                    \
  {                                                  \
    float* bs = reg + (S) * 128 + g * 4;             \
    float* bq = bs + NDOM * DIM;                     \
    float4 os = *(float4*)bs;                        \
    float4 oq = *(float4*)bq;                        \
    os.x += (V).x; os.y += (V).y; os.z += (V).z; os.w += (V).w; \
    oq.x = fmaf((V).x, (V).x, oq.x);                 \
    oq.y = fmaf((V).y, (V).y, oq.y);                 \
    oq.z = fmaf((V).z, (V).z, oq.z);                 \
    oq.w = fmaf((V).w, (V).w, oq.w);                 \
    *(float4*)bs = os;                               \
    *(float4*)bq = oq;                               \
  }
  for (int it = 0; it < rowsPerWave; it += 8) {
    const int r = row0 + it;
    const int4 sgA = *(const int4*)(seg + r);
    const int4 sgB = *(const int4*)(seg + r + 4);
    const float4 v0 = x4[(size_t)(r + 0 + h) * 32 + g];
    const float4 v1 = x4[(size_t)(r + 2 + h) * 32 + g];
    const float4 v2 = x4[(size_t)(r + 4 + h) * 32 + g];
    const float4 v3 = x4[(size_t)(r + 6 + h) * 32 + g];
    const int s0 = h ? sgA.y : sgA.x;
    const int s1 = h ? sgA.w : sgA.z;
    const int s2 = h ? sgB.y : sgB.x;
    const int s3 = h ? sgB.w : sgB.z;
    RMW(s0, v0) RMW(s1, v1) RMW(s2, v2) RMW(s3, v3)
  }
#undef RMW
  __syncthreads();
  for (int i = tid; i < rowsPerBlock; i += 256)
    atomicAdd(&lcnt[seg[blockIdx.x * rowsPerBlock + i]], 1.f);
  __syncthreads();
  float* outp = partials + (size_t)blockIdx.x * PENT;
  if (tid < NDOM) outp[tid] = lcnt[tid];
  for (int i = tid; i < 2 * NDOM * DIM; i += 256) {
    float v = 0.f;
#pragma unroll
    for (int rr = 0; rr < 8; ++rr) v += acc[rr * WREG + i];
    outp[NDOM + i] = v;
  }
}

__global__ __launch_bounds__(256) void pn_reduce2(const float* __restrict__ partials,
                                                  float* __restrict__ partials2,
                                                  int NB) {
  const int b = blockIdx.x;
  const int per = NB >> 6;
  const int b0 = b * per;
  const int tid = threadIdx.x;
  float acc[9];
#pragma unroll
  for (int i = 0; i < 9; ++i) acc[i] = 0.f;
  for (int j = b0; j < b0 + per; ++j) {
    const float* p = partials + (size_t)j * PENT;
#pragma unroll
    for (int i = 0; i < 9; ++i) {
      const int e = tid + i * 256;
      if (e < PENT) acc[i] += p[e];
    }
  }
  float* o = partials2 + (size_t)b * PENT;
#pragma unroll
  for (int i = 0; i < 9; ++i) {
    const int e = tid + i * 256;
    if (e < PENT) o[e] = acc[i];
  }
}

__global__ __launch_bounds__(256) void pn_finalize(const float* __restrict__ partials2,
                                                   const float* __restrict__ gg,
                                                   const float* __restrict__ gb,
                                                   const float* __restrict__ dg,
                                                   const float* __restrict__ db,
                                                   float* __restrict__ stats) {
  const int t = blockIdx.x * 256 + threadIdx.x;
  const int k = t >> 7;
  const int d = t & (DIM - 1);
  float c = 0.f, s = 0.f, q = 0.f;
  for (int j = 0; j < 64; ++j) {
    const float* p = partials2 + (size_t)j * PENT;
    c += p[k];
    s += p[NDOM + t];
    q += p[NDOM + NDOM * DIM + t];
  }
  const float n = fmaxf(c, 1.f);
  const float mean = s / n;
  const float var = fmaxf(q / n - mean * mean, 0.f);
  const float rstd = rsqrtf(var + EPSV);
  const float scale = (gg[d] + dg[t]) * rstd;
  const float shift = (gb[d] + db[t]) - scale * mean;
  stats[t] = scale;
  stats[NDOM * DIM + t] = shift;
}

__global__ __launch_bounds__(256) void pn_apply(const float* __restrict__ x,
                                                const int* __restrict__ seg,
                                                const float* __restrict__ stats,
                                                float* __restrict__ out) {
  const int g = blockIdx.x * 256 + threadIdx.x;
  const int row = g >> 5;
  const int c4 = g & 31;
  const int s = seg[row];
  const float4 xv = ((const float4*)x)[g];
  const float4 a = ((const float4*)(stats + s * DIM))[c4];
  const float4 b = ((const float4*)(stats + NDOM * DIM + s * DIM))[c4];
  float4 o;
  o.x = fmaf(xv.x, a.x, b.x);
  o.y = fmaf(xv.y, a.y, b.y);
  o.z = fmaf(xv.z, a.z, b.z);
  o.w = fmaf(xv.w, a.w, b.w);
  ((float4*)out)[g] = o;
}

extern "C" void kernel_launch(void* const* d_in, const int* in_sizes, int n_in,
                              void* d_out, int out_size, void* d_ws, size_t ws_size,
                              hipStream_t stream) {
  const float* x = (const float*)d_in[0];
  const float* gg = (const float*)d_in[1];
  const float* gb = (const float*)d_in[2];
  const float* dg = (const float*)d_in[3];
  const float* db = (const float*)d_in[4];
  const int* seg = (const int*)d_in[5];
  float* out = (float*)d_out;
  int B = in_sizes[5];  // 262144

  // co-resident grid: occupancy (expected 2/CU @ 64KB LDS) x CU count
  int occ = 2, ncu = 256;
  (void)hipOccupancyMaxActiveBlocksPerMultiprocessor(&occ, (const void*)pn_fused, 256, 0);
  if (occ < 1) occ = 1;
  if (occ > 2) occ = 2;
  int dev = 0;
  (void)hipGetDevice(&dev);
  (void)hipDeviceGetAttribute(&ncu, hipDeviceAttributeMultiprocessorCount, dev);
  if (ncu <= 0) ncu = 256;
  int nblk = occ * ncu;           // 512 expected
  while (B % (nblk * 4) != 0) nblk >>= 1;  // chunk must be multiple of 4 rows/wave step... keep pow2-safe
  if (nblk < 64) nblk = 64;

  // workspace: partials[nblk][PENT] | partials2[64][PENT] | stats[2048]
  float* partials = (float*)d_ws;
  float* partials2 = partials + (size_t)nblk * PENT;
  float* stats = partials2 + (size_t)64 * PENT;

  const float4* x4 = (const float4*)x;
  float4* out4 = (float4*)out;
  void* args[] = {(void*)&x4, (void*)&seg, (void*)&gg, (void*)&gb, (void*)&dg,
                  (void*)&db, (void*)&partials, (void*)&partials2, (void*)&stats,
                  (void*)&out4, (void*)&B};
  hipError_t err = hipLaunchCooperativeKernel((void*)pn_fused, dim3(nblk),
                                              dim3(256), args, 0, stream);
  if (err != hipSuccess) {
    // fallback: R10 4-kernel path (known-good)
    int NB = 1024;
    float* p1 = (float*)d_ws;
    float* p2 = p1 + (size_t)NB * PENT;
    float* st = p2 + (size_t)64 * PENT;
    const int rpb = B / NB;
    pn_reduce<<<NB, 256, 0, stream>>>((const float4*)x, seg, p1, rpb);
    pn_reduce2<<<64, 256, 0, stream>>>(p1, p2, NB);
    pn_finalize<<<4, 256, 0, stream>>>(p2, gg, gb, dg, db, st);
    const int nblk2 = (B * (DIM / 4)) / 256;
    pn_apply<<<nblk2, 256, 0, stream>>>(x, seg, st, out);
  }
}

// Round 12
// 124.059 us; speedup vs baseline: 1.4092x; 1.4092x over previous
//
#include <hip/hip_runtime.h>
#include <hip/hip_bf16.h>

// PartitionedNormalization: per-domain BN stats (training mode) + affine.
// out[B][128] f32 = (gg+dg[s])*(x-mean[s])*rsqrt(var[s]+eps) + (gb+db[s])
//
// R12: revert R11 fusion (174us, latency-bound at 2 blk/CU). R10 pn_reduce
// kept verbatim (verified race-free). finalize folded into reduce2 via
// last-block device-scope handshake; apply -> grid-stride 2048 blocks.

#define DIM 128
#define NDOM 8
#define PENT (NDOM + 2 * NDOM * DIM)  // 8 counts + 1024 sums + 1024 sqsums = 2056
#define EPSV 1e-3f
#define WREG 2048  // per half-wave region (floats): sums[8][128] | sqs[8][128]

// ---------------- pass 1: half-wave-private LDS accumulation (R10, verified) ----------------
__global__ __launch_bounds__(256) void pn_reduce(const float4* __restrict__ x4,
                                                 const int* __restrict__ seg,
                                                 float* __restrict__ partials,
                                                 int* __restrict__ counter,
                                                 int rowsPerBlock) {
  // zero the reduce2fin handshake counter once per call (stream-ordered
  // before pn_reduce2fin; device-scope store -> coherent point).
  if (blockIdx.x == 0 && threadIdx.x == 0)
    __hip_atomic_store(counter, 0, __ATOMIC_RELAXED, __HIP_MEMORY_SCOPE_AGENT);

  __shared__ float acc[8 * WREG];  // 64 KB -> 2 blocks/CU
  __shared__ float lcnt[NDOM];
  const int tid = threadIdx.x;
  const int w = tid >> 6;  // wave 0..3
  const int l = tid & 63;
  const int h = l >> 5;    // half-wave: row parity
  const int g = l & 31;    // float4 col group
  float* reg = acc + (w * 2 + h) * WREG;  // half-wave private

  for (int i = tid; i < 2 * WREG; i += 256)
    ((float4*)acc)[i] = make_float4(0.f, 0.f, 0.f, 0.f);
  if (tid < NDOM) lcnt[tid] = 0.f;
  __syncthreads();

  const int rowsPerWave = rowsPerBlock >> 2;  // 64
  const int row0 = blockIdx.x * rowsPerBlock + w * rowsPerWave;

#define RMW(S, V)                                    \
  {                                                  \
    float* bs = reg + (S) * 128 + g * 4;             \
    float* bq = bs + NDOM * DIM;                     \
    float4 os = *(float4*)bs;                        \
    float4 oq = *(float4*)bq;                        \
    os.x += (V).x;                                   \
    os.y += (V).y;                                   \
    os.z += (V).z;                                   \
    os.w += (V).w;                                   \
    oq.x = fmaf((V).x, (V).x, oq.x);                 \
    oq.y = fmaf((V).y, (V).y, oq.y);                 \
    oq.z = fmaf((V).z, (V).z, oq.z);                 \
    oq.w = fmaf((V).w, (V).w, oq.w);                 \
    *(float4*)bs = os;                               \
    *(float4*)bq = oq;                               \
  }
  for (int it = 0; it < rowsPerWave; it += 8) {
    const int r = row0 + it;
    const int4 sgA = *(const int4*)(seg + r);      // rows r..r+3
    const int4 sgB = *(const int4*)(seg + r + 4);  // rows r+4..r+7
    const float4 v0 = x4[(size_t)(r + 0 + h) * 32 + g];
    const float4 v1 = x4[(size_t)(r + 2 + h) * 32 + g];
    const float4 v2 = x4[(size_t)(r + 4 + h) * 32 + g];
    const float4 v3 = x4[(size_t)(r + 6 + h) * 32 + g];
    const int s0 = h ? sgA.y : sgA.x;
    const int s1 = h ? sgA.w : sgA.z;
    const int s2 = h ? sgB.y : sgB.x;
    const int s3 = h ? sgB.w : sgB.z;
    RMW(s0, v0)
    RMW(s1, v1)
    RMW(s2, v2)
    RMW(s3, v3)
  }
#undef RMW
  __syncthreads();

  for (int i = tid; i < rowsPerBlock; i += 256)
    atomicAdd(&lcnt[seg[blockIdx.x * rowsPerBlock + i]], 1.f);
  __syncthreads();

  float* outp = partials + (size_t)blockIdx.x * PENT;
  if (tid < NDOM) outp[tid] = lcnt[tid];
  for (int i = tid; i < 2 * NDOM * DIM; i += 256) {
    float v = 0.f;
#pragma unroll
    for (int rr = 0; rr < 8; ++rr) v += acc[rr * WREG + i];
    outp[NDOM + i] = v;
  }
}

// ---------------- pass 2: reduce NB->64, last block finalizes ----------------
// Producer blocks: write partials2 row, __threadfence (device release), agent
// atomicAdd. Last block: acquire via the atomic, reads all 64 rows (its XCD L2
// holds only rows its own XCD wrote -> coherent; others miss to L3), computes
// the scale/shift table, resets the counter for the next call.
__global__ __launch_bounds__(256) void pn_reduce2fin(
    const float* __restrict__ partials, float* __restrict__ partials2,
    const float* __restrict__ gg, const float* __restrict__ gb,
    const float* __restrict__ dg, const float* __restrict__ db,
    float* __restrict__ stats, int* __restrict__ counter, int NB) {
  const int b = blockIdx.x;  // 0..63
  const int per = NB >> 6;
  const int b0 = b * per;
  const int tid = threadIdx.x;
  float acc[9];
#pragma unroll
  for (int i = 0; i < 9; ++i) acc[i] = 0.f;
  for (int j = b0; j < b0 + per; ++j) {
    const float* p = partials + (size_t)j * PENT;
#pragma unroll
    for (int i = 0; i < 9; ++i) {
      const int e = tid + i * 256;
      if (e < PENT) acc[i] += p[e];
    }
  }
  float* o = partials2 + (size_t)b * PENT;
#pragma unroll
  for (int i = 0; i < 9; ++i) {
    const int e = tid + i * 256;
    if (e < PENT) o[e] = acc[i];
  }

  __threadfence();  // release partials2 row to device scope
  __shared__ int isLast;
  if (tid == 0) {
    const int old = __hip_atomic_fetch_add(counter, 1, __ATOMIC_ACQ_REL,
                                           __HIP_MEMORY_SCOPE_AGENT);
    isLast = (old == 63);
  }
  __syncthreads();
  if (!isLast) return;
  if (tid == 0)
    __hip_atomic_store(counter, 0, __ATOMIC_RELAXED, __HIP_MEMORY_SCOPE_AGENT);

  // finalize: 256 threads x 4 outputs
  for (int t = tid; t < NDOM * DIM; t += 256) {
    const int k = t >> 7;
    const int d = t & (DIM - 1);
    float c = 0.f, s = 0.f, q = 0.f;
    for (int j = 0; j < 64; ++j) {
      const float* p = partials2 + (size_t)j * PENT;
      c += p[k];
      s += p[NDOM + t];
      q += p[NDOM + NDOM * DIM + t];
    }
    const float n = fmaxf(c, 1.f);
    const float mean = s / n;
    const float var = fmaxf(q / n - mean * mean, 0.f);
    const float rstd = rsqrtf(var + EPSV);
    const float scale = (gg[d] + dg[t]) * rstd;  // dg[k*128+d] == dg[t]
    const float shift = (gb[d] + db[t]) - scale * mean;
    stats[t] = scale;
    stats[NDOM * DIM + t] = shift;
  }
}

// ---------------- pass 3: normalize, grid-stride (G11) ----------------
__global__ __launch_bounds__(256) void pn_apply(const float4* __restrict__ x4,
                                                const int* __restrict__ seg,
                                                const float* __restrict__ stats,
                                                float4* __restrict__ out,
                                                int nf4) {
  const int stride = gridDim.x * 256;
#pragma unroll 4
  for (int gi = blockIdx.x * 256 + threadIdx.x; gi < nf4; gi += stride) {
    const int row = gi >> 5;  // 32 float4 per row
    const int c4 = gi & 31;
    const int s = seg[row];
    const float4 xv = x4[gi];
    const float4 a = ((const float4*)(stats + s * DIM))[c4];
    const float4 b = ((const float4*)(stats + NDOM * DIM + s * DIM))[c4];
    float4 o;
    o.x = fmaf(xv.x, a.x, b.x);
    o.y = fmaf(xv.y, a.y, b.y);
    o.z = fmaf(xv.z, a.z, b.z);
    o.w = fmaf(xv.w, a.w, b.w);
    out[gi] = o;
  }
}

extern "C" void kernel_launch(void* const* d_in, const int* in_sizes, int n_in,
                              void* d_out, int out_size, void* d_ws, size_t ws_size,
                              hipStream_t stream) {
  const float* x = (const float*)d_in[0];
  const float* gg = (const float*)d_in[1];
  const float* gb = (const float*)d_in[2];
  const float* dg = (const float*)d_in[3];
  const float* db = (const float*)d_in[4];
  const int* seg = (const int*)d_in[5];
  float* out = (float*)d_out;
  const int B = in_sizes[5];  // 262144

  // workspace: partials[NB][PENT] | partials2[64][PENT] | stats[2048] | counter
  const int NB = 1024;
  float* partials = (float*)d_ws;
  float* partials2 = partials + (size_t)NB * PENT;
  float* stats = partials2 + (size_t)64 * PENT;
  int* counter = (int*)(stats + 2 * NDOM * DIM);

  const int rpb = B / NB;  // 256 rows/block; 64 contiguous rows/wave

  pn_reduce<<<NB, 256, 0, stream>>>((const float4*)x, seg, partials, counter, rpb);
  pn_reduce2fin<<<64, 256, 0, stream>>>(partials, partials2, gg, gb, dg, db,
                                        stats, counter, NB);
  const int nf4 = B * (DIM / 4);  // 8388608
  pn_apply<<<2048, 256, 0, stream>>>((const float4*)x, seg, stats,
                                     (float4*)out, nf4);
}

// Round 13
// 123.409 us; speedup vs baseline: 1.4167x; 1.0053x over previous
//
#include <hip/hip_runtime.h>
#include <hip/hip_bf16.h>

// PartitionedNormalization: per-domain BN stats (training mode) + affine.
// out[B][128] f32 = (gg+dg[s])*(x-mean[s])*rsqrt(var[s]+eps) + (gb+db[s])
//
// R13: single-variable experiment vs R12 (+23us over R10): revert ONLY
// pn_apply to the one-shot 32768-block form (all good runs used it);
// keep the reduce2fin last-block fusion.

#define DIM 128
#define NDOM 8
#define PENT (NDOM + 2 * NDOM * DIM)  // 8 counts + 1024 sums + 1024 sqsums = 2056
#define EPSV 1e-3f
#define WREG 2048  // per half-wave region (floats): sums[8][128] | sqs[8][128]

// ---------------- pass 1: half-wave-private LDS accumulation (R10, verified) ----------------
__global__ __launch_bounds__(256) void pn_reduce(const float4* __restrict__ x4,
                                                 const int* __restrict__ seg,
                                                 float* __restrict__ partials,
                                                 int* __restrict__ counter,
                                                 int rowsPerBlock) {
  if (blockIdx.x == 0 && threadIdx.x == 0)
    __hip_atomic_store(counter, 0, __ATOMIC_RELAXED, __HIP_MEMORY_SCOPE_AGENT);

  __shared__ float acc[8 * WREG];  // 64 KB -> 2 blocks/CU
  __shared__ float lcnt[NDOM];
  const int tid = threadIdx.x;
  const int w = tid >> 6;  // wave 0..3
  const int l = tid & 63;
  const int h = l >> 5;    // half-wave: row parity
  const int g = l & 31;    // float4 col group
  float* reg = acc + (w * 2 + h) * WREG;  // half-wave private

  for (int i = tid; i < 2 * WREG; i += 256)
    ((float4*)acc)[i] = make_float4(0.f, 0.f, 0.f, 0.f);
  if (tid < NDOM) lcnt[tid] = 0.f;
  __syncthreads();

  const int rowsPerWave = rowsPerBlock >> 2;  // 64
  const int row0 = blockIdx.x * rowsPerBlock + w * rowsPerWave;

#define RMW(S, V)                                    \
  {                                                  \
    float* bs = reg + (S) * 128 + g * 4;             \
    float* bq = bs + NDOM * DIM;                     \
    float4 os = *(float4*)bs;                        \
    float4 oq = *(float4*)bq;                        \
    os.x += (V).x;                                   \
    os.y += (V).y;                                   \
    os.z += (V).z;                                   \
    os.w += (V).w;                                   \
    oq.x = fmaf((V).x, (V).x, oq.x);                 \
    oq.y = fmaf((V).y, (V).y, oq.y);                 \
    oq.z = fmaf((V).z, (V).z, oq.z);                 \
    oq.w = fmaf((V).w, (V).w, oq.w);                 \
    *(float4*)bs = os;                               \
    *(float4*)bq = oq;                               \
  }
  for (int it = 0; it < rowsPerWave; it += 8) {
    const int r = row0 + it;
    const int4 sgA = *(const int4*)(seg + r);      // rows r..r+3
    const int4 sgB = *(const int4*)(seg + r + 4);  // rows r+4..r+7
    const float4 v0 = x4[(size_t)(r + 0 + h) * 32 + g];
    const float4 v1 = x4[(size_t)(r + 2 + h) * 32 + g];
    const float4 v2 = x4[(size_t)(r + 4 + h) * 32 + g];
    const float4 v3 = x4[(size_t)(r + 6 + h) * 32 + g];
    const int s0 = h ? sgA.y : sgA.x;
    const int s1 = h ? sgA.w : sgA.z;
    const int s2 = h ? sgB.y : sgB.x;
    const int s3 = h ? sgB.w : sgB.z;
    RMW(s0, v0)
    RMW(s1, v1)
    RMW(s2, v2)
    RMW(s3, v3)
  }
#undef RMW
  __syncthreads();

  for (int i = tid; i < rowsPerBlock; i += 256)
    atomicAdd(&lcnt[seg[blockIdx.x * rowsPerBlock + i]], 1.f);
  __syncthreads();

  float* outp = partials + (size_t)blockIdx.x * PENT;
  if (tid < NDOM) outp[tid] = lcnt[tid];
  for (int i = tid; i < 2 * NDOM * DIM; i += 256) {
    float v = 0.f;
#pragma unroll
    for (int rr = 0; rr < 8; ++rr) v += acc[rr * WREG + i];
    outp[NDOM + i] = v;
  }
}

// ---------------- pass 2: reduce NB->64, last block finalizes ----------------
__global__ __launch_bounds__(256) void pn_reduce2fin(
    const float* __restrict__ partials, float* __restrict__ partials2,
    const float* __restrict__ gg, const float* __restrict__ gb,
    const float* __restrict__ dg, const float* __restrict__ db,
    float* __restrict__ stats, int* __restrict__ counter, int NB) {
  const int b = blockIdx.x;  // 0..63
  const int per = NB >> 6;
  const int b0 = b * per;
  const int tid = threadIdx.x;
  float acc[9];
#pragma unroll
  for (int i = 0; i < 9; ++i) acc[i] = 0.f;
  for (int j = b0; j < b0 + per; ++j) {
    const float* p = partials + (size_t)j * PENT;
#pragma unroll
    for (int i = 0; i < 9; ++i) {
      const int e = tid + i * 256;
      if (e < PENT) acc[i] += p[e];
    }
  }
  float* o = partials2 + (size_t)b * PENT;
#pragma unroll
  for (int i = 0; i < 9; ++i) {
    const int e = tid + i * 256;
    if (e < PENT) o[e] = acc[i];
  }

  __threadfence();  // release partials2 row to device scope
  __shared__ int isLast;
  if (tid == 0) {
    const int old = __hip_atomic_fetch_add(counter, 1, __ATOMIC_ACQ_REL,
                                           __HIP_MEMORY_SCOPE_AGENT);
    isLast = (old == 63);
  }
  __syncthreads();
  if (!isLast) return;
  if (tid == 0)
    __hip_atomic_store(counter, 0, __ATOMIC_RELAXED, __HIP_MEMORY_SCOPE_AGENT);

  for (int t = tid; t < NDOM * DIM; t += 256) {
    const int k = t >> 7;
    const int d = t & (DIM - 1);
    float c = 0.f, s = 0.f, q = 0.f;
    for (int j = 0; j < 64; ++j) {
      const float* p = partials2 + (size_t)j * PENT;
      c += p[k];
      s += p[NDOM + t];
      q += p[NDOM + NDOM * DIM + t];
    }
    const float n = fmaxf(c, 1.f);
    const float mean = s / n;
    const float var = fmaxf(q / n - mean * mean, 0.f);
    const float rstd = rsqrtf(var + EPSV);
    const float scale = (gg[d] + dg[t]) * rstd;  // dg[k*128+d] == dg[t]
    const float shift = (gb[d] + db[t]) - scale * mean;
    stats[t] = scale;
    stats[NDOM * DIM + t] = shift;
  }
}

// ---------------- pass 3: normalize — one-shot, 1 float4/thread (R10 form) ----------------
__global__ __launch_bounds__(256) void pn_apply(const float* __restrict__ x,
                                                const int* __restrict__ seg,
                                                const float* __restrict__ stats,
                                                float* __restrict__ out) {
  const int g = blockIdx.x * 256 + threadIdx.x;  // float4 index
  const int row = g >> 5;                        // 32 float4 per row
  const int c4 = g & 31;
  const int s = seg[row];
  const float4 xv = ((const float4*)x)[g];
  const float4 a = ((const float4*)(stats + s * DIM))[c4];
  const float4 b = ((const float4*)(stats + NDOM * DIM + s * DIM))[c4];
  float4 o;
  o.x = fmaf(xv.x, a.x, b.x);
  o.y = fmaf(xv.y, a.y, b.y);
  o.z = fmaf(xv.z, a.z, b.z);
  o.w = fmaf(xv.w, a.w, b.w);
  ((float4*)out)[g] = o;
}

extern "C" void kernel_launch(void* const* d_in, const int* in_sizes, int n_in,
                              void* d_out, int out_size, void* d_ws, size_t ws_size,
                              hipStream_t stream) {
  const float* x = (const float*)d_in[0];
  const float* gg = (const float*)d_in[1];
  const float* gb = (const float*)d_in[2];
  const float* dg = (const float*)d_in[3];
  const float* db = (const float*)d_in[4];
  const int* seg = (const int*)d_in[5];
  float* out = (float*)d_out;
  const int B = in_sizes[5];  // 262144

  // workspace: partials[NB][PENT] | partials2[64][PENT] | stats[2048] | counter
  const int NB = 1024;
  float* partials = (float*)d_ws;
  float* partials2 = partials + (size_t)NB * PENT;
  float* stats = partials2 + (size_t)64 * PENT;
  int* counter = (int*)(stats + 2 * NDOM * DIM);

  const int rpb = B / NB;  // 256 rows/block; 64 contiguous rows/wave

  pn_reduce<<<NB, 256, 0, stream>>>((const float4*)x, seg, partials, counter, rpb);
  pn_reduce2fin<<<64, 256, 0, stream>>>(partials, partials2, gg, gb, dg, db,
                                        stats, counter, NB);
  const int nblk = (B * (DIM / 4)) / 256;  // 32768
  pn_apply<<<nblk, 256, 0, stream>>>(x, seg, stats, out);
}

// Round 14
// 91.755 us; speedup vs baseline: 1.9054x; 1.3450x over previous
//
#include <hip/hip_runtime.h>
#include <hip/hip_bf16.h>

// PartitionedNormalization: per-domain BN stats (training mode) + affine.
// out[B][128] f32 = (gg+dg[s])*(x-mean[s])*rsqrt(var[s]+eps) + (gb+db[s])
//
// R14: revert R12/R13 handshake (measured +22us: device-scope fence+atomic
// in 64 blocks ~ L2 wb/inv cost). Exact R10 4-kernel structure; single
// change vs R10: NB 1024 -> 512 (one co-resident round, half the partials).

#define DIM 128
#define NDOM 8
#define PENT (NDOM + 2 * NDOM * DIM)  // 8 counts + 1024 sums + 1024 sqsums = 2056
#define EPSV 1e-3f
#define WREG 2048  // per half-wave region (floats): sums[8][128] | sqs[8][128]

// ---------------- pass 1: half-wave-private LDS accumulation (R10, verified) ----------------
__global__ __launch_bounds__(256) void pn_reduce(const float4* __restrict__ x4,
                                                 const int* __restrict__ seg,
                                                 float* __restrict__ partials,
                                                 int rowsPerBlock) {
  __shared__ float acc[8 * WREG];  // 64 KB -> 2 blocks/CU
  __shared__ float lcnt[NDOM];
  const int tid = threadIdx.x;
  const int w = tid >> 6;  // wave 0..3
  const int l = tid & 63;
  const int h = l >> 5;    // half-wave: row parity
  const int g = l & 31;    // float4 col group
  float* reg = acc + (w * 2 + h) * WREG;  // half-wave private

  for (int i = tid; i < 2 * WREG; i += 256)
    ((float4*)acc)[i] = make_float4(0.f, 0.f, 0.f, 0.f);
  if (tid < NDOM) lcnt[tid] = 0.f;
  __syncthreads();

  const int rowsPerWave = rowsPerBlock >> 2;
  const int row0 = blockIdx.x * rowsPerBlock + w * rowsPerWave;

#define RMW(S, V)                                    \
  {                                                  \
    float* bs = reg + (S) * 128 + g * 4;             \
    float* bq = bs + NDOM * DIM;                     \
    float4 os = *(float4*)bs;                        \
    float4 oq = *(float4*)bq;                        \
    os.x += (V).x;                                   \
    os.y += (V).y;                                   \
    os.z += (V).z;                                   \
    os.w += (V).w;                                   \
    oq.x = fmaf((V).x, (V).x, oq.x);                 \
    oq.y = fmaf((V).y, (V).y, oq.y);                 \
    oq.z = fmaf((V).z, (V).z, oq.z);                 \
    oq.w = fmaf((V).w, (V).w, oq.w);                 \
    *(float4*)bs = os;                               \
    *(float4*)bq = oq;                               \
  }
  for (int it = 0; it < rowsPerWave; it += 8) {
    const int r = row0 + it;
    const int4 sgA = *(const int4*)(seg + r);      // rows r..r+3
    const int4 sgB = *(const int4*)(seg + r + 4);  // rows r+4..r+7
    const float4 v0 = x4[(size_t)(r + 0 + h) * 32 + g];
    const float4 v1 = x4[(size_t)(r + 2 + h) * 32 + g];
    const float4 v2 = x4[(size_t)(r + 4 + h) * 32 + g];
    const float4 v3 = x4[(size_t)(r + 6 + h) * 32 + g];
    const int s0 = h ? sgA.y : sgA.x;
    const int s1 = h ? sgA.w : sgA.z;
    const int s2 = h ? sgB.y : sgB.x;
    const int s3 = h ? sgB.w : sgB.z;
    RMW(s0, v0)
    RMW(s1, v1)
    RMW(s2, v2)
    RMW(s3, v3)
  }
#undef RMW
  __syncthreads();

  for (int i = tid; i < rowsPerBlock; i += 256)
    atomicAdd(&lcnt[seg[blockIdx.x * rowsPerBlock + i]], 1.f);
  __syncthreads();

  float* outp = partials + (size_t)blockIdx.x * PENT;
  if (tid < NDOM) outp[tid] = lcnt[tid];
  for (int i = tid; i < 2 * NDOM * DIM; i += 256) {
    float v = 0.f;
#pragma unroll
    for (int rr = 0; rr < 8; ++rr) v += acc[rr * WREG + i];
    outp[NDOM + i] = v;
  }
}

// ---------------- pass 2a: reduce NB partial rows -> 64 ----------------
__global__ __launch_bounds__(256) void pn_reduce2(const float* __restrict__ partials,
                                                  float* __restrict__ partials2,
                                                  int NB) {
  const int b = blockIdx.x;  // 0..63
  const int per = NB >> 6;   // NB is pow2 >= 64
  const int b0 = b * per;
  const int tid = threadIdx.x;
  float acc[9];
#pragma unroll
  for (int i = 0; i < 9; ++i) acc[i] = 0.f;
  for (int j = b0; j < b0 + per; ++j) {
    const float* p = partials + (size_t)j * PENT;
#pragma unroll
    for (int i = 0; i < 9; ++i) {
      const int e = tid + i * 256;
      if (e < PENT) acc[i] += p[e];
    }
  }
  float* o = partials2 + (size_t)b * PENT;
#pragma unroll
  for (int i = 0; i < 9; ++i) {
    const int e = tid + i * 256;
    if (e < PENT) o[e] = acc[i];
  }
}

// ---------------- pass 2b: final reduce + scale/shift table (4 blocks) ----------------
__global__ __launch_bounds__(256) void pn_finalize(const float* __restrict__ partials2,
                                                   const float* __restrict__ gg,
                                                   const float* __restrict__ gb,
                                                   const float* __restrict__ dg,
                                                   const float* __restrict__ db,
                                                   float* __restrict__ stats) {
  const int t = blockIdx.x * 256 + threadIdx.x;  // (k = t>>7, d = t&127)
  const int k = t >> 7;
  const int d = t & (DIM - 1);
  float c = 0.f, s = 0.f, q = 0.f;
  for (int j = 0; j < 64; ++j) {
    const float* p = partials2 + (size_t)j * PENT;
    c += p[k];
    s += p[NDOM + t];
    q += p[NDOM + NDOM * DIM + t];
  }
  const float n = fmaxf(c, 1.f);
  const float mean = s / n;
  const float var = fmaxf(q / n - mean * mean, 0.f);
  const float rstd = rsqrtf(var + EPSV);
  const float scale = (gg[d] + dg[t]) * rstd;  // dg[k*128+d] == dg[t]
  const float shift = (gb[d] + db[t]) - scale * mean;
  stats[t] = scale;
  stats[NDOM * DIM + t] = shift;
}

// ---------------- pass 3: normalize (one-shot, 1 float4/thread) ----------------
__global__ __launch_bounds__(256) void pn_apply(const float* __restrict__ x,
                                                const int* __restrict__ seg,
                                                const float* __restrict__ stats,
                                                float* __restrict__ out) {
  const int g = blockIdx.x * 256 + threadIdx.x;  // float4 index
  const int row = g >> 5;                        // 32 float4 per row
  const int c4 = g & 31;
  const int s = seg[row];
  const float4 xv = ((const float4*)x)[g];
  const float4 a = ((const float4*)(stats + s * DIM))[c4];
  const float4 b = ((const float4*)(stats + NDOM * DIM + s * DIM))[c4];
  float4 o;
  o.x = fmaf(xv.x, a.x, b.x);
  o.y = fmaf(xv.y, a.y, b.y);
  o.z = fmaf(xv.z, a.z, b.z);
  o.w = fmaf(xv.w, a.w, b.w);
  ((float4*)out)[g] = o;
}

extern "C" void kernel_launch(void* const* d_in, const int* in_sizes, int n_in,
                              void* d_out, int out_size, void* d_ws, size_t ws_size,
                              hipStream_t stream) {
  const float* x = (const float*)d_in[0];
  const float* gg = (const float*)d_in[1];
  const float* gb = (const float*)d_in[2];
  const float* dg = (const float*)d_in[3];
  const float* db = (const float*)d_in[4];
  const int* seg = (const int*)d_in[5];
  float* out = (float*)d_out;
  const int B = in_sizes[5];  // 262144

  // workspace: partials[NB][PENT] | partials2[64][PENT] | stats[2048]
  const int NB = 512;  // 2 blocks/CU, exactly one co-resident round
  float* partials = (float*)d_ws;
  float* partials2 = partials + (size_t)NB * PENT;
  float* stats = partials2 + (size_t)64 * PENT;

  const int rpb = B / NB;  // 512 rows/block; 128 contiguous rows/wave

  pn_reduce<<<NB, 256, 0, stream>>>((const float4*)x, seg, partials, rpb);
  pn_reduce2<<<64, 256, 0, stream>>>(partials, partials2, NB);
  pn_finalize<<<4, 256, 0, stream>>>(partials2, gg, gb, dg, db, stats);

  const int nblk = (B * (DIM / 4)) / 256;  // 32768
  pn_apply<<<nblk, 256, 0, stream>>>(x, seg, stats, out);
}